// Round 1
// baseline (149.548 us; speedup 1.0000x reference)
//
#include <hip/hip_runtime.h>

// focal_loss scalar reduction:
//   out = COEF * sum_i [ idx==0 ? log(p_i) : idx==1 ? log1p(-p_i) : 0 ]
// Memory-bound: 134 MB read @ ~6.3 TB/s -> ~21 us floor.
// Strategy: accumulate log2(x) per thread (HW v_log_f32 is log2), scale the
// final scalar by COEF*ln2 once. Two-kernel tree reduction (no atomics, so no
// d_out zero-init needed under the harness's 0xAA poison).

static constexpr int BLOCK = 256;
static constexpr int GRID  = 2048;              // 8 blocks/CU -> 32 waves/CU
static constexpr float COEF = 0.004f;           // WF * (1-0.8)^2
static constexpr float LN2  = 0.69314718055994530942f;

__global__ __launch_bounds__(BLOCK) void fl_partial(
    const float* __restrict__ p,
    const int*   __restrict__ idx,
    float*       __restrict__ partials,
    int n)
{
    const float4* __restrict__ p4 = reinterpret_cast<const float4*>(p);
    const int4*   __restrict__ i4 = reinterpret_cast<const int4*>(idx);
    const int n4 = n >> 2;
    const int tid = blockIdx.x * BLOCK + threadIdx.x;
    const int stride = GRID * BLOCK;

    float acc = 0.0f;
    for (int i = tid; i < n4; i += stride) {
        float4 pv = p4[i];
        int4   iv = i4[i];
        // idx is {0,1}: select p or 1-p, one hardware log2 each.
        float x0 = (iv.x == 0) ? pv.x : 1.0f - pv.x;
        float x1 = (iv.y == 0) ? pv.y : 1.0f - pv.y;
        float x2 = (iv.z == 0) ? pv.z : 1.0f - pv.z;
        float x3 = (iv.w == 0) ? pv.w : 1.0f - pv.w;
        acc += __log2f(x0);
        acc += __log2f(x1);
        acc += __log2f(x2);
        acc += __log2f(x3);
    }
    // scalar tail (N is a multiple of 4, but stay robust)
    if (tid == 0) {
        for (int i = n4 << 2; i < n; ++i) {
            float x = (idx[i] == 0) ? p[i] : 1.0f - p[i];
            acc += __log2f(x);
        }
    }

    // wave-64 butterfly reduce
    for (int off = 32; off > 0; off >>= 1)
        acc += __shfl_down(acc, off, 64);

    __shared__ float ws[BLOCK / 64];
    const int lane = threadIdx.x & 63;
    const int wave = threadIdx.x >> 6;
    if (lane == 0) ws[wave] = acc;
    __syncthreads();
    if (threadIdx.x == 0)
        partials[blockIdx.x] = ws[0] + ws[1] + ws[2] + ws[3];
}

__global__ __launch_bounds__(BLOCK) void fl_final(
    const float* __restrict__ partials,
    float*       __restrict__ out)
{
    float acc = 0.0f;
    for (int i = threadIdx.x; i < GRID; i += BLOCK)
        acc += partials[i];
    for (int off = 32; off > 0; off >>= 1)
        acc += __shfl_down(acc, off, 64);

    __shared__ float ws[BLOCK / 64];
    const int lane = threadIdx.x & 63;
    const int wave = threadIdx.x >> 6;
    if (lane == 0) ws[wave] = acc;
    __syncthreads();
    if (threadIdx.x == 0)
        out[0] = (ws[0] + ws[1] + ws[2] + ws[3]) * (COEF * LN2);
}

extern "C" void kernel_launch(void* const* d_in, const int* in_sizes, int n_in,
                              void* d_out, int out_size, void* d_ws, size_t ws_size,
                              hipStream_t stream)
{
    const float* p   = (const float*)d_in[0];
    const int*   idx = (const int*)d_in[1];
    float* partials  = (float*)d_ws;      // GRID floats = 8 KB scratch
    const int n = in_sizes[0];

    fl_partial<<<GRID, BLOCK, 0, stream>>>(p, idx, partials, n);
    fl_final<<<1, BLOCK, 0, stream>>>(partials, (float*)d_out);
}

// Round 2
// 143.631 us; speedup vs baseline: 1.0412x; 1.0412x over previous
//
#include <hip/hip_runtime.h>

// focal_loss scalar reduction:
//   out = COEF * sum_i [ idx==0 ? log(p_i) : idx==1 ? log1p(-p_i) : 0 ]
//
// R1 post-mortem: latency-bound (VGPR=12 -> 1 outstanding 32B load-pair/wave
// -> Little's law 3.1 TB/s, matching measurement). Fix: unroll x4 so each
// wave keeps 128 B in flight; cap VGPR at 64 (__launch_bounds__(256,8)) to
// hold 8 waves/SIMD. 32 waves/CU x 128 B = 4 KB outstanding -> ~12 TB/s
// ceiling, past the HBM/L3 limit -> kernel becomes truly memory-bound.

static constexpr int BLOCK = 256;
static constexpr int GRID  = 2048;              // 8 blocks/CU
static constexpr float COEF = 0.004f;           // WF * (1-0.8)^2
static constexpr float LN2  = 0.69314718055994530942f;

__device__ __forceinline__ float sel_log2(float pv, int iv) {
    // idx in {0,1}: log2(p) or log2(1-p)
    return __log2f((iv == 0) ? pv : 1.0f - pv);
}

__global__ __launch_bounds__(BLOCK, 8) void fl_partial(
    const float* __restrict__ p,
    const int*   __restrict__ idx,
    float*       __restrict__ partials,
    int n)
{
    const float4* __restrict__ p4 = reinterpret_cast<const float4*>(p);
    const int4*   __restrict__ i4 = reinterpret_cast<const int4*>(idx);
    const int n4 = n >> 2;
    const int stride = GRID * BLOCK;
    int i = blockIdx.x * BLOCK + threadIdx.x;

    float acc = 0.0f;

    // Unroll x4: 8 independent 16B loads in flight before any use.
    for (; i + 3 * stride < n4; i += 4 * stride) {
        float4 pv0 = p4[i];
        float4 pv1 = p4[i + stride];
        float4 pv2 = p4[i + 2 * stride];
        float4 pv3 = p4[i + 3 * stride];
        int4   iv0 = i4[i];
        int4   iv1 = i4[i + stride];
        int4   iv2 = i4[i + 2 * stride];
        int4   iv3 = i4[i + 3 * stride];

        acc += sel_log2(pv0.x, iv0.x); acc += sel_log2(pv0.y, iv0.y);
        acc += sel_log2(pv0.z, iv0.z); acc += sel_log2(pv0.w, iv0.w);
        acc += sel_log2(pv1.x, iv1.x); acc += sel_log2(pv1.y, iv1.y);
        acc += sel_log2(pv1.z, iv1.z); acc += sel_log2(pv1.w, iv1.w);
        acc += sel_log2(pv2.x, iv2.x); acc += sel_log2(pv2.y, iv2.y);
        acc += sel_log2(pv2.z, iv2.z); acc += sel_log2(pv2.w, iv2.w);
        acc += sel_log2(pv3.x, iv3.x); acc += sel_log2(pv3.y, iv3.y);
        acc += sel_log2(pv3.z, iv3.z); acc += sel_log2(pv3.w, iv3.w);
    }
    // remainder chunks
    for (; i < n4; i += stride) {
        float4 pv = p4[i];
        int4   iv = i4[i];
        acc += sel_log2(pv.x, iv.x); acc += sel_log2(pv.y, iv.y);
        acc += sel_log2(pv.z, iv.z); acc += sel_log2(pv.w, iv.w);
    }
    // scalar tail (n % 4)
    if (blockIdx.x == 0 && threadIdx.x == 0) {
        for (int j = n4 << 2; j < n; ++j)
            acc += sel_log2(p[j], idx[j]);
    }

    // wave-64 butterfly reduce
    for (int off = 32; off > 0; off >>= 1)
        acc += __shfl_down(acc, off, 64);

    __shared__ float ws[BLOCK / 64];
    const int lane = threadIdx.x & 63;
    const int wave = threadIdx.x >> 6;
    if (lane == 0) ws[wave] = acc;
    __syncthreads();
    if (threadIdx.x == 0)
        partials[blockIdx.x] = ws[0] + ws[1] + ws[2] + ws[3];
}

__global__ __launch_bounds__(BLOCK) void fl_final(
    const float* __restrict__ partials,
    float*       __restrict__ out)
{
    float acc = 0.0f;
    for (int i = threadIdx.x; i < GRID; i += BLOCK)
        acc += partials[i];
    for (int off = 32; off > 0; off >>= 1)
        acc += __shfl_down(acc, off, 64);

    __shared__ float ws[BLOCK / 64];
    const int lane = threadIdx.x & 63;
    const int wave = threadIdx.x >> 6;
    if (lane == 0) ws[wave] = acc;
    __syncthreads();
    if (threadIdx.x == 0)
        out[0] = (ws[0] + ws[1] + ws[2] + ws[3]) * (COEF * LN2);
}

extern "C" void kernel_launch(void* const* d_in, const int* in_sizes, int n_in,
                              void* d_out, int out_size, void* d_ws, size_t ws_size,
                              hipStream_t stream)
{
    const float* p   = (const float*)d_in[0];
    const int*   idx = (const int*)d_in[1];
    float* partials  = (float*)d_ws;      // GRID floats = 8 KB scratch
    const int n = in_sizes[0];

    fl_partial<<<GRID, BLOCK, 0, stream>>>(p, idx, partials, n);
    fl_final<<<1, BLOCK, 0, stream>>>(partials, (float*)d_out);
}